// Round 1
// baseline (92.781 us; speedup 1.0000x reference)
//
#include <hip/hip_runtime.h>
#include <hip/hip_bf16.h>

namespace {

constexpr int Hh    = 16;
constexpr int LL    = 4096;
constexpr int DD    = 64;
constexpr int BH    = 4 * 16;        // B*H
constexpr int CHUNK = 256;           // rows per block
constexpr int NCH   = LL / CHUNK;    // 16 chunks per (b,h)
constexpr float EPS = 1e-6f;

__device__ __forceinline__ float elu1(float x) {
    // elu(x)+1 = x+1 (x>0) else exp(x)
    return x > 0.0f ? x + 1.0f : __expf(x);
}

// Pass 1: per-chunk totals of kf and kf*v  ->  ws record of 128 floats per (bh, chunk)
__global__ __launch_bounds__(256) void la_pass1(
    const float* __restrict__ kp, const float* __restrict__ vp,
    const float* __restrict__ maskp, float* __restrict__ ws)
{
    const int blk  = blockIdx.x;
    const int bh   = blk / NCH;
    const int ch   = blk - bh * NCH;
    const int b    = bh / Hh;
    const int t    = threadIdx.x;
    const int qd   = t & 15;      // channel quad: d = qd*4 .. qd*4+3
    const int team = t >> 4;      // 16 teams of 16 threads

    const long base = ((long)bh * LL + (long)ch * CHUNK) * DD;
    const float* mrow = maskp + (long)b * LL + (long)ch * CHUNK;

    float sk0=0.f, sk1=0.f, sk2=0.f, sk3=0.f;
    float sv0=0.f, sv1=0.f, sv2=0.f, sv3=0.f;

    #pragma unroll 4
    for (int r = 0; r < CHUNK / 16; ++r) {
        const int row = r * 16 + team;          // block reads 16 contiguous rows/iter
        const long off = base + (long)row * DD + qd * 4;
        const float4 k4 = *(const float4*)(kp + off);
        const float4 v4 = *(const float4*)(vp + off);
        const float  m  = mrow[row];
        const float kf0 = elu1(k4.x) * m;
        const float kf1 = elu1(k4.y) * m;
        const float kf2 = elu1(k4.z) * m;
        const float kf3 = elu1(k4.w) * m;
        sk0 += kf0;              sk1 += kf1;
        sk2 += kf2;              sk3 += kf3;
        sv0 += kf0 * (v4.x * m); sv1 += kf1 * (v4.y * m);
        sv2 += kf2 * (v4.z * m); sv3 += kf3 * (v4.w * m);
    }

    __shared__ float lds[256][8];
    lds[t][0]=sk0; lds[t][1]=sk1; lds[t][2]=sk2; lds[t][3]=sk3;
    lds[t][4]=sv0; lds[t][5]=sv1; lds[t][6]=sv2; lds[t][7]=sv3;
    __syncthreads();

    // tree-reduce across the 16 teams (stride 16 threads)
    for (int s = 8; s >= 1; s >>= 1) {
        if (team < s) {
            #pragma unroll
            for (int j = 0; j < 8; ++j) lds[t][j] += lds[t + s * 16][j];
        }
        __syncthreads();
    }

    if (team == 0) {
        float* rec = ws + ((long)bh * NCH + ch) * 128;
        #pragma unroll
        for (int j = 0; j < 4; ++j) {
            rec[qd * 4 + j]      = lds[t][j];     // k-sum per channel
            rec[64 + qd * 4 + j] = lds[t][4 + j]; // kv-sum per channel
        }
    }
}

// Pass 2: carry-in from predecessor chunks + in-block scan + output
__global__ __launch_bounds__(256) void la_pass2(
    const float* __restrict__ qp, const float* __restrict__ kp,
    const float* __restrict__ vp, const float* __restrict__ maskp,
    const float* __restrict__ ws, float* __restrict__ outp)
{
    const int blk  = blockIdx.x;
    const int bh   = blk / NCH;
    const int ch   = blk - bh * NCH;
    const int b    = bh / Hh;
    const int t    = threadIdx.x;
    const int qd   = t & 15;
    const int team = t >> 4;

    const long base = ((long)bh * LL + (long)ch * CHUNK) * DD;
    const float* mrow = maskp + (long)b * LL + (long)ch * CHUNK;

    // carry from chunks < ch (records are tiny and L2-hot)
    float ck0=0.f, ck1=0.f, ck2=0.f, ck3=0.f;
    float cv0=0.f, cv1=0.f, cv2=0.f, cv3=0.f;
    for (int c = 0; c < ch; ++c) {
        const float* rec = ws + ((long)bh * NCH + c) * 128;
        ck0 += rec[qd*4+0]; ck1 += rec[qd*4+1];
        ck2 += rec[qd*4+2]; ck3 += rec[qd*4+3];
        cv0 += rec[64+qd*4+0]; cv1 += rec[64+qd*4+1];
        cv2 += rec[64+qd*4+2]; cv3 += rec[64+qd*4+3];
    }

    // step 1: this team's 16-row totals (rows team*16 .. team*16+15)
    float tk0=0.f, tk1=0.f, tk2=0.f, tk3=0.f;
    float tv0=0.f, tv1=0.f, tv2=0.f, tv3=0.f;
    #pragma unroll 4
    for (int r = 0; r < 16; ++r) {
        const int row = team * 16 + r;
        const long off = base + (long)row * DD + qd * 4;
        const float4 k4 = *(const float4*)(kp + off);
        const float4 v4 = *(const float4*)(vp + off);
        const float  m  = mrow[row];
        const float kf0 = elu1(k4.x) * m;
        const float kf1 = elu1(k4.y) * m;
        const float kf2 = elu1(k4.z) * m;
        const float kf3 = elu1(k4.w) * m;
        tk0 += kf0;              tk1 += kf1;
        tk2 += kf2;              tk3 += kf3;
        tv0 += kf0 * (v4.x * m); tv1 += kf1 * (v4.y * m);
        tv2 += kf2 * (v4.z * m); tv3 += kf3 * (v4.w * m);
    }

    __shared__ float lds[256][8];
    lds[t][0]=tk0; lds[t][1]=tk1; lds[t][2]=tk2; lds[t][3]=tk3;
    lds[t][4]=tv0; lds[t][5]=tv1; lds[t][6]=tv2; lds[t][7]=tv3;
    __syncthreads();

    // exclusive scan over teams (team index < mine), per channel quad
    float ek0=0.f, ek1=0.f, ek2=0.f, ek3=0.f;
    float ev0=0.f, ev1=0.f, ev2=0.f, ev3=0.f;
    for (int tm = 0; tm < team; ++tm) {
        const int idx = tm * 16 + qd;
        ek0 += lds[idx][0]; ek1 += lds[idx][1];
        ek2 += lds[idx][2]; ek3 += lds[idx][3];
        ev0 += lds[idx][4]; ev1 += lds[idx][5];
        ev2 += lds[idx][6]; ev3 += lds[idx][7];
    }

    // running inclusive state entering this team's rows
    float rk0 = ck0 + ek0, rk1 = ck1 + ek1, rk2 = ck2 + ek2, rk3 = ck3 + ek3;
    float rv0 = cv0 + ev0, rv1 = cv1 + ev1, rv2 = cv2 + ev2, rv3 = cv3 + ev3;

    // step 2: serial scan over the team's 16 rows, emit output
    #pragma unroll 4
    for (int r = 0; r < 16; ++r) {
        const int row = team * 16 + r;
        const long off = base + (long)row * DD + qd * 4;
        const float4 k4 = *(const float4*)(kp + off);
        const float4 v4 = *(const float4*)(vp + off);
        const float4 q4 = *(const float4*)(qp + off);
        const float  m  = mrow[row];

        const float kf0 = elu1(k4.x) * m;
        const float kf1 = elu1(k4.y) * m;
        const float kf2 = elu1(k4.z) * m;
        const float kf3 = elu1(k4.w) * m;
        rk0 += kf0;              rk1 += kf1;
        rk2 += kf2;              rk3 += kf3;
        rv0 += kf0 * (v4.x * m); rv1 += kf1 * (v4.y * m);
        rv2 += kf2 * (v4.z * m); rv3 += kf3 * (v4.w * m);

        const float qf0 = elu1(q4.x);
        const float qf1 = elu1(q4.y);
        const float qf2 = elu1(q4.z);
        const float qf3 = elu1(q4.w);

        float pz = qf0*rk0 + qf1*rk1 + qf2*rk2 + qf3*rk3;
        // reduce across the 16 lanes of this team (teams are 16-lane aligned)
        pz += __shfl_xor(pz, 1);
        pz += __shfl_xor(pz, 2);
        pz += __shfl_xor(pz, 4);
        pz += __shfl_xor(pz, 8);

        const float z   = (pz + EPS) * m;
        const float inv = 1.0f / z;

        float4 o;
        o.x = qf0 * rv0 * inv;
        o.y = qf1 * rv1 * inv;
        o.z = qf2 * rv2 * inv;
        o.w = qf3 * rv3 * inv;
        *(float4*)(outp + off) = o;
    }
}

} // namespace

extern "C" void kernel_launch(void* const* d_in, const int* in_sizes, int n_in,
                              void* d_out, int out_size, void* d_ws, size_t ws_size,
                              hipStream_t stream) {
    const float* q    = (const float*)d_in[0];
    const float* k    = (const float*)d_in[1];
    const float* v    = (const float*)d_in[2];
    const float* mask = (const float*)d_in[3];
    float* out = (float*)d_out;
    float* ws  = (float*)d_ws;   // needs BH*NCH*128 floats = 512 KiB

    dim3 grid(BH * NCH);
    dim3 block(256);
    la_pass1<<<grid, block, 0, stream>>>(k, v, mask, ws);
    la_pass2<<<grid, block, 0, stream>>>(q, k, v, mask, ws, out);
}